// Round 17
// baseline (187.502 us; speedup 1.0000x reference)
//
#include <hip/hip_runtime.h>

#define N_NODES 100000
#define N_EDGES 1600000
#define IN_F 64
#define HID 128
#define N_CLS 64

#define NPB2 256                                 // nodes per bucket (d >> 8)
#define NBK2 ((N_NODES + NPB2 - 1) / NPB2)       // 391
#define NPBLK 512                                // scatter blocks
#define PCHUNK (N_EDGES / NPBLK)                 // 3125 edges per block (exact)
#define CVTBLK ((N_NODES * 64 / 8 + 255) / 256)  // 3125 cvt blocks

// ================= bf16 helpers =================
__device__ __forceinline__ unsigned short f2bf(float f) {
    unsigned int u = __float_as_uint(f);
    u = (u + 0x7FFFu + ((u >> 16) & 1u)) >> 16;   // RNE
    return (unsigned short)u;
}
__device__ __forceinline__ float bf2f(unsigned short h) {
    return __uint_as_float(((unsigned int)h) << 16);
}

// ================= generic helpers =================
__global__ void k_zero_f4(float4* __restrict__ p, int n4) {
    int i = blockIdx.x * blockDim.x + threadIdx.x;
    if (i < n4) p[i] = make_float4(0.f, 0.f, 0.f, 0.f);
}
__global__ void k_init_bias(float* __restrict__ out, const float* __restrict__ b2, int n) {
    int i = blockIdx.x * blockDim.x + threadIdx.x;
    if (i < n) out[i] = b2[i & 63];
}

// ================= fused: fp32->bf16 convert + per-(block,bucket) counts =================
__global__ __launch_bounds__(256) void k_cvt_count(const float4* __restrict__ x4,
                                                   uint4* __restrict__ xh,
                                                   const int* __restrict__ dst,
                                                   int* __restrict__ C) {
    __shared__ int h[NBK2];
    const int t = threadIdx.x;
    if (blockIdx.x < NPBLK) {
        for (int i = t; i < NBK2; i += 256) h[i] = 0;
        __syncthreads();
        const int e0 = blockIdx.x * PCHUNK;
        int e1 = e0 + PCHUNK; if (e1 > N_EDGES) e1 = N_EDGES;
        for (int e = e0 + t; e < e1; e += 256) atomicAdd(&h[dst[e] >> 8], 1);
        __syncthreads();
        for (int i = t; i < NBK2; i += 256) C[blockIdx.x * NBK2 + i] = h[i];
    } else {
        int i = (blockIdx.x - NPBLK) * 256 + t;
        const int n8 = N_NODES * 64 / 8;
        if (i < n8) {
            float4 a = x4[2 * i], b = x4[2 * i + 1];
            uint4 o;
            o.x = (unsigned)f2bf(a.x) | ((unsigned)f2bf(a.y) << 16);
            o.y = (unsigned)f2bf(a.z) | ((unsigned)f2bf(a.w) << 16);
            o.z = (unsigned)f2bf(b.x) | ((unsigned)f2bf(b.y) << 16);
            o.w = (unsigned)f2bf(b.z) | ((unsigned)f2bf(b.w) << 16);
            xh[i] = o;
        }
    }
}

// 2) per-bucket column scan of C (in place -> exclusive offsets); emit totals
__global__ __launch_bounds__(NPBLK) void k_colscan(int* __restrict__ C,
                                                   int* __restrict__ btot) {
    __shared__ int sc[2][NPBLK];
    const int t = threadIdx.x;
    const int bucket = blockIdx.x;
    int v = C[t * NBK2 + bucket];
    sc[0][t] = v;
    __syncthreads();
    int cur = 0;
    for (int d = 1; d < NPBLK; d <<= 1) {
        int x = sc[cur][t];
        if (t >= d) x += sc[cur][t - d];
        sc[cur ^ 1][t] = x;
        __syncthreads();
        cur ^= 1;
    }
    C[t * NBK2 + bucket] = sc[cur][t] - v;            // exclusive within bucket
    if (t == NPBLK - 1) btot[bucket] = sc[cur][t];    // bucket total
}

// 3) scatter into exactly-reserved spans; boff recomputed in-block from btot
__global__ __launch_bounds__(256) void k_scat(const int* __restrict__ src,
                                              const int* __restrict__ dst,
                                              const int* __restrict__ C,
                                              const int* __restrict__ btot,
                                              int* __restrict__ eb) {
    __shared__ int gbase[NBK2];
    __shared__ int lcur[NBK2];
    __shared__ int sc[2][256];
    const int t = threadIdx.x;
    int v0 = (2 * t < NBK2) ? btot[2 * t] : 0;
    int v1 = (2 * t + 1 < NBK2) ? btot[2 * t + 1] : 0;
    int s = v0 + v1;
    sc[0][t] = s;
    __syncthreads();
    int cur = 0;
    for (int d = 1; d < 256; d <<= 1) {
        int x = sc[cur][t];
        if (t >= d) x += sc[cur][t - d];
        sc[cur ^ 1][t] = x;
        __syncthreads();
        cur ^= 1;
    }
    int exp = sc[cur][t] - s;
    if (2 * t < NBK2) {
        gbase[2 * t] = exp + C[blockIdx.x * NBK2 + 2 * t];
        lcur[2 * t] = 0;
    }
    if (2 * t + 1 < NBK2) {
        gbase[2 * t + 1] = exp + v0 + C[blockIdx.x * NBK2 + 2 * t + 1];
        lcur[2 * t + 1] = 0;
    }
    __syncthreads();
    const int e0 = blockIdx.x * PCHUNK;
    int e1 = e0 + PCHUNK; if (e1 > N_EDGES) e1 = N_EDGES;
    for (int e = e0 + t; e < e1; e += 256) {
        int d = dst[e];
        int b = d >> 8;
        int r = atomicAdd(&lcur[b], 1);
        eb[gbase[b] + r] = ((d & 255) << 17) | src[e];   // dstLow(8b) | src(17b)
    }
}

// 4) per-bucket: node hist + scan -> off; sort -> es; boff recomputed from btot
__global__ __launch_bounds__(256) void k_fill3(const int* __restrict__ eb,
                                               const int* __restrict__ btot,
                                               int* __restrict__ off,
                                               int* __restrict__ es) {
    __shared__ int ldeg[NPB2];
    __shared__ int sc[2][NPB2];
    __shared__ int sh_base, sh_end;
    const int t = threadIdx.x;
    const int b = blockIdx.x;

    int v0 = (2 * t < NBK2) ? btot[2 * t] : 0;
    int v1 = (2 * t + 1 < NBK2) ? btot[2 * t + 1] : 0;
    int s = v0 + v1;
    sc[0][t] = s;
    __syncthreads();
    int cur = 0;
    for (int d = 1; d < 256; d <<= 1) {
        int x = sc[cur][t];
        if (t >= d) x += sc[cur][t - d];
        sc[cur ^ 1][t] = x;
        __syncthreads();
        cur ^= 1;
    }
    int exp = sc[cur][t] - s;
    if (2 * t == b)     { sh_base = exp;          sh_end = exp + v0; }
    if (2 * t + 1 == b) { sh_base = exp + v0;     sh_end = exp + v0 + v1; }
    __syncthreads();
    const int bbase = sh_base, bend = sh_end;

    ldeg[t] = 0;
    __syncthreads();
    for (int i = bbase + t; i < bend; i += 256) atomicAdd(&ldeg[eb[i] >> 17], 1);
    __syncthreads();

    int v = ldeg[t];
    sc[0][t] = v;
    __syncthreads();
    cur = 0;
    for (int d = 1; d < NPB2; d <<= 1) {
        int x = sc[cur][t];
        if (t >= d) x += sc[cur][t - d];
        sc[cur ^ 1][t] = x;
        __syncthreads();
        cur ^= 1;
    }
    int ex = sc[cur][t] - v;

    const int n0 = b * NPB2;
    if (n0 + t < N_NODES) off[n0 + t] = bbase + ex;
    if (b == NBK2 - 1 && t == 0) off[N_NODES] = N_EDGES;

    ldeg[t] = ex;
    __syncthreads();

    for (int i = bbase + t; i < bend; i += 256) {
        int p = eb[i];
        int r = atomicAdd(&ldeg[p >> 17], 1);
        es[bbase + r] = p & 0x1FFFF;
    }
}

// ================= gather (bf16 feat, 8 nodes/wave, 8 lanes/node) =================
// OUTBF=1: write bf16 row to outh. OUTBF=0: write fp32 row (+bias) to out.
template <int OUTBF>
__global__ __launch_bounds__(256) void k_gather8(const uint4* __restrict__ feat,
                                                 const int* __restrict__ es,
                                                 const int* __restrict__ off,
                                                 const float* __restrict__ bias,
                                                 float* __restrict__ out,
                                                 unsigned short* __restrict__ outh) {
    const int wave = threadIdx.x >> 6;
    const int lane = threadIdx.x & 63;
    const int grp = lane >> 3;                 // 0..7
    const int l8 = lane & 7;
    const int n = blockIdx.x * 32 + wave * 8 + grp;   // 3125*32 == N_NODES exactly
    const int beg = off[n], end = off[n + 1];
    const int gb = grp << 3;
    float a0 = 0.f, a1 = 0.f, a2 = 0.f, a3 = 0.f;
    float a4 = 0.f, a5 = 0.f, a6 = 0.f, a7 = 0.f;
    for (int base = beg; base < end; base += 8) {
        int m = end - base; if (m > 8) m = 8;
        int id = (l8 < m) ? es[base + l8] : 0;
        int k = 0;
        for (; k + 4 <= m; k += 4) {
            int s0 = __shfl(id, gb | (k + 0));
            int s1 = __shfl(id, gb | (k + 1));
            int s2 = __shfl(id, gb | (k + 2));
            int s3 = __shfl(id, gb | (k + 3));
            uint4 u0 = feat[(unsigned)s0 * 8u + l8];
            uint4 u1 = feat[(unsigned)s1 * 8u + l8];
            uint4 u2 = feat[(unsigned)s2 * 8u + l8];
            uint4 u3 = feat[(unsigned)s3 * 8u + l8];
            a0 += (__uint_as_float(u0.x << 16) + __uint_as_float(u1.x << 16))
                + (__uint_as_float(u2.x << 16) + __uint_as_float(u3.x << 16));
            a1 += (__uint_as_float(u0.x & 0xFFFF0000u) + __uint_as_float(u1.x & 0xFFFF0000u))
                + (__uint_as_float(u2.x & 0xFFFF0000u) + __uint_as_float(u3.x & 0xFFFF0000u));
            a2 += (__uint_as_float(u0.y << 16) + __uint_as_float(u1.y << 16))
                + (__uint_as_float(u2.y << 16) + __uint_as_float(u3.y << 16));
            a3 += (__uint_as_float(u0.y & 0xFFFF0000u) + __uint_as_float(u1.y & 0xFFFF0000u))
                + (__uint_as_float(u2.y & 0xFFFF0000u) + __uint_as_float(u3.y & 0xFFFF0000u));
            a4 += (__uint_as_float(u0.z << 16) + __uint_as_float(u1.z << 16))
                + (__uint_as_float(u2.z << 16) + __uint_as_float(u3.z << 16));
            a5 += (__uint_as_float(u0.z & 0xFFFF0000u) + __uint_as_float(u1.z & 0xFFFF0000u))
                + (__uint_as_float(u2.z & 0xFFFF0000u) + __uint_as_float(u3.z & 0xFFFF0000u));
            a6 += (__uint_as_float(u0.w << 16) + __uint_as_float(u1.w << 16))
                + (__uint_as_float(u2.w << 16) + __uint_as_float(u3.w << 16));
            a7 += (__uint_as_float(u0.w & 0xFFFF0000u) + __uint_as_float(u1.w & 0xFFFF0000u))
                + (__uint_as_float(u2.w & 0xFFFF0000u) + __uint_as_float(u3.w & 0xFFFF0000u));
        }
        for (; k < m; ++k) {
            int s = __shfl(id, gb | k);
            uint4 u = feat[(unsigned)s * 8u + l8];
            a0 += __uint_as_float(u.x << 16);
            a1 += __uint_as_float(u.x & 0xFFFF0000u);
            a2 += __uint_as_float(u.y << 16);
            a3 += __uint_as_float(u.y & 0xFFFF0000u);
            a4 += __uint_as_float(u.z << 16);
            a5 += __uint_as_float(u.z & 0xFFFF0000u);
            a6 += __uint_as_float(u.w << 16);
            a7 += __uint_as_float(u.w & 0xFFFF0000u);
        }
    }
    if (OUTBF) {
        uint4 w;
        w.x = (unsigned)f2bf(a0) | ((unsigned)f2bf(a1) << 16);
        w.y = (unsigned)f2bf(a2) | ((unsigned)f2bf(a3) << 16);
        w.z = (unsigned)f2bf(a4) | ((unsigned)f2bf(a5) << 16);
        w.w = (unsigned)f2bf(a6) | ((unsigned)f2bf(a7) << 16);
        *(uint4*)&outh[(size_t)n * 64 + l8 * 8] = w;
    } else {
        if (bias) {
            float4 b0 = *(const float4*)&bias[l8 * 8];
            float4 b1 = *(const float4*)&bias[l8 * 8 + 4];
            a0 += b0.x; a1 += b0.y; a2 += b0.z; a3 += b0.w;
            a4 += b1.x; a5 += b1.y; a6 += b1.z; a7 += b1.w;
        }
        float4 o0, o1;
        o0.x = a0; o0.y = a1; o0.z = a2; o0.w = a3;
        o1.x = a4; o1.y = a5; o1.z = a6; o1.w = a7;
        *(float4*)&out[(size_t)n * 64 + l8 * 8] = o0;
        *(float4*)&out[(size_t)n * 64 + l8 * 8 + 4] = o1;
    }
}

// ================= fallback atomic scatter =================
__global__ void k_scatter64(const float* __restrict__ feat,
                            const int* __restrict__ src,
                            const int* __restrict__ dst,
                            float* __restrict__ out) {
    int i = blockIdx.x * blockDim.x + threadIdx.x;
    int e = i >> 4;
    if (e >= N_EDGES) return;
    int j = (i & 15) << 2;
    int s = src[e];
    int d = dst[e];
    float4 v = *reinterpret_cast<const float4*>(feat + (size_t)s * 64 + j);
    float* o = out + (size_t)d * 64 + j;
    atomicAdd(o + 0, v.x);
    atomicAdd(o + 1, v.y);
    atomicAdd(o + 2, v.z);
    atomicAdd(o + 3, v.w);
}

// ================= fused bf16 MLP: zh = bf16(relu(Ah*W1+b1)*W2) =================
#define MROWS 32
#define XS_S 68      // float stride (fallback MLP)
#define XSB_S 72     // ushort stride for bf16 x rows (144 B, 16B-aligned)
#define HSB_S 136    // ushort stride for bf16 h rows (272 B, 16B-aligned)

__device__ __forceinline__ void fma4(float4& a, float s, const float4& wv) {
    a.x = fmaf(s, wv.x, a.x);
    a.y = fmaf(s, wv.y, a.y);
    a.z = fmaf(s, wv.z, a.z);
    a.w = fmaf(s, wv.w, a.w);
}

__global__ __launch_bounds__(256, 3) void k_mlpB(const unsigned short* __restrict__ Ah,
                                                 unsigned short* __restrict__ zh,
                                                 const float* __restrict__ W1,
                                                 const float* __restrict__ b1,
                                                 const float* __restrict__ W2) {
    __shared__ float Ws[64 * 128];                  // 32 KB: W1 then W2
    __shared__ unsigned short xs[MROWS * XSB_S];    // 4.6 KB bf16 x
    __shared__ unsigned short hs[MROWS * HSB_S];    // 8.7 KB bf16 h
    __shared__ float b1s[128];
    const int t = threadIdx.x;
    const int row0 = blockIdx.x * MROWS;

    // stage W1
    {
        const float4* w4 = (const float4*)W1;
        float4* s4 = (float4*)Ws;
        for (int i = t; i < 2048; i += 256) s4[i] = w4[i];
    }
    // early-issue W2 into regs (latency hides under phase 1)
    float4 w2r[8];
    {
        const float4* w4 = (const float4*)W2;
#pragma unroll
        for (int i = 0; i < 8; ++i) w2r[i] = w4[t + i * 256];
    }
    if (t < 128) b1s[t] = b1[t];
    // stage Ah rows: 32 rows x 64 bf16 = 256 uint4
    {
        int r = t >> 3, k8 = t & 7;
        uint4 v = *(const uint4*)&Ah[(size_t)(row0 + r) * 64 + k8 * 8];
        *(uint4*)&xs[r * XSB_S + k8 * 8] = v;
    }
    __syncthreads();

    // ---- phase 1: h = relu(x*W1 + b1), 4 rows x 4 cols per thread ----
    {
        const int rg = t >> 5, cg = t & 31;
        const int r0 = rg * 4, c0 = cg * 4;
        float4 bv = *(const float4*)&b1s[c0];
        float4 acc0 = bv, acc1 = bv, acc2 = bv, acc3 = bv;
#pragma unroll 4
        for (int k4 = 0; k4 < 16; ++k4) {
            ushort4 ua0 = *(const ushort4*)&xs[(r0 + 0) * XSB_S + k4 * 4];
            ushort4 ua1 = *(const ushort4*)&xs[(r0 + 1) * XSB_S + k4 * 4];
            ushort4 ua2 = *(const ushort4*)&xs[(r0 + 2) * XSB_S + k4 * 4];
            ushort4 ua3 = *(const ushort4*)&xs[(r0 + 3) * XSB_S + k4 * 4];
            float4 w0 = *(const float4*)&Ws[(k4 * 4 + 0) * 128 + c0];
            float4 w1 = *(const float4*)&Ws[(k4 * 4 + 1) * 128 + c0];
            float4 w2 = *(const float4*)&Ws[(k4 * 4 + 2) * 128 + c0];
            float4 w3 = *(const float4*)&Ws[(k4 * 4 + 3) * 128 + c0];
            fma4(acc0, bf2f(ua0.x), w0); fma4(acc0, bf2f(ua0.y), w1);
            fma4(acc0, bf2f(ua0.z), w2); fma4(acc0, bf2f(ua0.w), w3);
            fma4(acc1, bf2f(ua1.x), w0); fma4(acc1, bf2f(ua1.y), w1);
            fma4(acc1, bf2f(ua1.z), w2); fma4(acc1, bf2f(ua1.w), w3);
            fma4(acc2, bf2f(ua2.x), w0); fma4(acc2, bf2f(ua2.y), w1);
            fma4(acc2, bf2f(ua2.z), w2); fma4(acc2, bf2f(ua2.w), w3);
            fma4(acc3, bf2f(ua3.x), w0); fma4(acc3, bf2f(ua3.y), w1);
            fma4(acc3, bf2f(ua3.z), w2); fma4(acc3, bf2f(ua3.w), w3);
        }
        ushort4 hq;
        hq.x = f2bf(fmaxf(acc0.x, 0.f)); hq.y = f2bf(fmaxf(acc0.y, 0.f));
        hq.z = f2bf(fmaxf(acc0.z, 0.f)); hq.w = f2bf(fmaxf(acc0.w, 0.f));
        *(ushort4*)&hs[(r0 + 0) * HSB_S + c0] = hq;
        hq.x = f2bf(fmaxf(acc1.x, 0.f)); hq.y = f2bf(fmaxf(acc1.y, 0.f));
        hq.z = f2bf(fmaxf(acc1.z, 0.f)); hq.w = f2bf(fmaxf(acc1.w, 0.f));
        *(ushort4*)&hs[(r0 + 1) * HSB_S + c0] = hq;
        hq.x = f2bf(fmaxf(acc2.x, 0.f)); hq.y = f2bf(fmaxf(acc2.y, 0.f));
        hq.z = f2bf(fmaxf(acc2.z, 0.f)); hq.w = f2bf(fmaxf(acc2.w, 0.f));
        *(ushort4*)&hs[(r0 + 2) * HSB_S + c0] = hq;
        hq.x = f2bf(fmaxf(acc3.x, 0.f)); hq.y = f2bf(fmaxf(acc3.y, 0.f));
        hq.z = f2bf(fmaxf(acc3.z, 0.f)); hq.w = f2bf(fmaxf(acc3.w, 0.f));
        *(ushort4*)&hs[(r0 + 3) * HSB_S + c0] = hq;
    }
    __syncthreads();

    // write W2 registers into Ws (no memory wait)
    {
        float4* s4 = (float4*)Ws;
#pragma unroll
        for (int i = 0; i < 8; ++i) s4[t + i * 256] = w2r[i];
    }
    __syncthreads();

    // ---- phase 2: z = h*W2, 2 rows x 4 cols per thread ----
    {
        const int rg = t >> 4, cg = t & 15;
        const int r0 = rg * 2, c0 = cg * 4;
        float4 acc0 = make_float4(0.f, 0.f, 0.f, 0.f);
        float4 acc1 = make_float4(0.f, 0.f, 0.f, 0.f);
#pragma unroll 4
        for (int k4 = 0; k4 < 32; ++k4) {
            ushort4 u0 = *(const ushort4*)&hs[(r0 + 0) * HSB_S + k4 * 4];
            ushort4 u1 = *(const ushort4*)&hs[(r0 + 1) * HSB_S + k4 * 4];
            float4 w0 = *(const float4*)&Ws[(k4 * 4 + 0) * 64 + c0];
            float4 w1 = *(const float4*)&Ws[(k4 * 4 + 1) * 64 + c0];
            float4 w2 = *(const float4*)&Ws[(k4 * 4 + 2) * 64 + c0];
            float4 w3 = *(const float4*)&Ws[(k4 * 4 + 3) * 64 + c0];
            fma4(acc0, bf2f(u0.x), w0); fma4(acc0, bf2f(u0.y), w1);
            fma4(acc0, bf2f(u0.z), w2); fma4(acc0, bf2f(u0.w), w3);
            fma4(acc1, bf2f(u1.x), w0); fma4(acc1, bf2f(u1.y), w1);
            fma4(acc1, bf2f(u1.z), w2); fma4(acc1, bf2f(u1.w), w3);
        }
        ushort4 o0, o1;
        o0.x = f2bf(acc0.x); o0.y = f2bf(acc0.y); o0.z = f2bf(acc0.z); o0.w = f2bf(acc0.w);
        o1.x = f2bf(acc1.x); o1.y = f2bf(acc1.y); o1.z = f2bf(acc1.z); o1.w = f2bf(acc1.w);
        *(ushort4*)&zh[(size_t)(row0 + r0 + 0) * 64 + c0] = o0;
        *(ushort4*)&zh[(size_t)(row0 + r0 + 1) * 64 + c0] = o1;
    }
}

// fp32 in-place MLP (fallback)
__global__ __launch_bounds__(256, 2) void k_mlpF(float* __restrict__ A,
                                                 const float* __restrict__ W1,
                                                 const float* __restrict__ b1,
                                                 const float* __restrict__ W2) {
    __shared__ float Ws[64 * 128];
    __shared__ float xs[MROWS * XS_S];
    __shared__ float hs[MROWS * 132];
    __shared__ float b1s[128];
    const int t = threadIdx.x;
    const int row0 = blockIdx.x * MROWS;

    {
        const float4* w4 = (const float4*)W1;
        float4* s4 = (float4*)Ws;
        for (int i = t; i < 2048; i += 256) s4[i] = w4[i];
    }
    if (t < 128) b1s[t] = b1[t];
#pragma unroll
    for (int c = 0; c < 2; ++c) {
        int lin = t + c * 256;
        int r = lin >> 4, k4 = lin & 15;
        float4 v = *(const float4*)(A + (size_t)(row0 + r) * 64 + k4 * 4);
        *(float4*)&xs[r * XS_S + k4 * 4] = v;
    }
    __syncthreads();
    {
        const int rg = t >> 5, cg = t & 31;
        const int r0 = rg * 4, c0 = cg * 4;
        float4 bv = *(const float4*)&b1s[c0];
        float4 acc0 = bv, acc1 = bv, acc2 = bv, acc3 = bv;
#pragma unroll 4
        for (int k4 = 0; k4 < 16; ++k4) {
            float4 a0 = *(const float4*)&xs[(r0 + 0) * XS_S + k4 * 4];
            float4 a1 = *(const float4*)&xs[(r0 + 1) * XS_S + k4 * 4];
            float4 a2 = *(const float4*)&xs[(r0 + 2) * XS_S + k4 * 4];
            float4 a3 = *(const float4*)&xs[(r0 + 3) * XS_S + k4 * 4];
            float4 w0 = *(const float4*)&Ws[(k4 * 4 + 0) * 128 + c0];
            float4 w1 = *(const float4*)&Ws[(k4 * 4 + 1) * 128 + c0];
            float4 w2 = *(const float4*)&Ws[(k4 * 4 + 2) * 128 + c0];
            float4 w3 = *(const float4*)&Ws[(k4 * 4 + 3) * 128 + c0];
            fma4(acc0, a0.x, w0); fma4(acc0, a0.y, w1); fma4(acc0, a0.z, w2); fma4(acc0, a0.w, w3);
            fma4(acc1, a1.x, w0); fma4(acc1, a1.y, w1); fma4(acc1, a1.z, w2); fma4(acc1, a1.w, w3);
            fma4(acc2, a2.x, w0); fma4(acc2, a2.y, w1); fma4(acc2, a2.z, w2); fma4(acc2, a2.w, w3);
            fma4(acc3, a3.x, w0); fma4(acc3, a3.y, w1); fma4(acc3, a3.z, w2); fma4(acc3, a3.w, w3);
        }
        float4 h;
        h.x = fmaxf(acc0.x, 0.f); h.y = fmaxf(acc0.y, 0.f); h.z = fmaxf(acc0.z, 0.f); h.w = fmaxf(acc0.w, 0.f);
        *(float4*)&hs[(r0 + 0) * 132 + c0] = h;
        h.x = fmaxf(acc1.x, 0.f); h.y = fmaxf(acc1.y, 0.f); h.z = fmaxf(acc1.z, 0.f); h.w = fmaxf(acc1.w, 0.f);
        *(float4*)&hs[(r0 + 1) * 132 + c0] = h;
        h.x = fmaxf(acc2.x, 0.f); h.y = fmaxf(acc2.y, 0.f); h.z = fmaxf(acc2.z, 0.f); h.w = fmaxf(acc2.w, 0.f);
        *(float4*)&hs[(r0 + 2) * 132 + c0] = h;
        h.x = fmaxf(acc3.x, 0.f); h.y = fmaxf(acc3.y, 0.f); h.z = fmaxf(acc3.z, 0.f); h.w = fmaxf(acc3.w, 0.f);
        *(float4*)&hs[(r0 + 3) * 132 + c0] = h;
    }
    __syncthreads();
    {
        const float4* w4 = (const float4*)W2;
        float4* s4 = (float4*)Ws;
        for (int i = t; i < 2048; i += 256) s4[i] = w4[i];
    }
    __syncthreads();
    {
        const int rg = t >> 4, cg = t & 15;
        const int r0 = rg * 2, c0 = cg * 4;
        float4 acc0 = make_float4(0.f, 0.f, 0.f, 0.f);
        float4 acc1 = make_float4(0.f, 0.f, 0.f, 0.f);
#pragma unroll 4
        for (int k4 = 0; k4 < 32; ++k4) {
            float4 h0 = *(const float4*)&hs[(r0 + 0) * 132 + k4 * 4];
            float4 h1 = *(const float4*)&hs[(r0 + 1) * 132 + k4 * 4];
            float4 w0 = *(const float4*)&Ws[(k4 * 4 + 0) * 64 + c0];
            float4 w1 = *(const float4*)&Ws[(k4 * 4 + 1) * 64 + c0];
            float4 w2 = *(const float4*)&Ws[(k4 * 4 + 2) * 64 + c0];
            float4 w3 = *(const float4*)&Ws[(k4 * 4 + 3) * 64 + c0];
            fma4(acc0, h0.x, w0); fma4(acc0, h0.y, w1); fma4(acc0, h0.z, w2); fma4(acc0, h0.w, w3);
            fma4(acc1, h1.x, w0); fma4(acc1, h1.y, w1); fma4(acc1, h1.z, w2); fma4(acc1, h1.w, w3);
        }
        *(float4*)(A + (size_t)(row0 + r0 + 0) * 64 + c0) = acc0;
        *(float4*)(A + (size_t)(row0 + r0 + 1) * 64 + c0) = acc1;
    }
}

static inline size_t alignup(size_t v, size_t a) { return (v + a - 1) & ~(a - 1); }

extern "C" void kernel_launch(void* const* d_in, const int* in_sizes, int n_in,
                              void* d_out, int out_size, void* d_ws, size_t ws_size,
                              hipStream_t stream) {
    const float* x  = (const float*)d_in[0];
    const float* W1 = (const float*)d_in[1];
    const float* b1 = (const float*)d_in[2];
    const float* W2 = (const float*)d_in[3];
    const float* b2 = (const float*)d_in[4];
    const int* src  = (const int*)d_in[5];
    const int* dst  = (const int*)d_in[6];
    float* out = (float*)d_out;

    const int nfeat = N_NODES * 64;
    const int nfeat4 = nfeat / 4;

    // ---- tier-1 layout (64B-aligned fields) ----
    char* base = (char*)d_ws;
    size_t o = 0;
    size_t o_xh   = o;   o = alignup(o + (size_t)nfeat * 2, 64);            // 12.8 MB (zh aliases)
    size_t o_es   = o;   o = alignup(o + (size_t)N_EDGES * 4, 64);          // 6.4 MB
    size_t o_off  = o;   o = alignup(o + (size_t)(N_NODES + 1) * 4, 64);
    size_t o_C    = o;   o = alignup(o + (size_t)NPBLK * NBK2 * 4, 64);     // 800 KB
    size_t o_btot = o;   o = alignup(o + (size_t)NBK2 * 4, 64);
    size_t o_Ah   = o;   o = alignup(o + (size_t)nfeat * 2, 64);            // 12.8 MB bf16 agg
    size_t o_eb   = o;   o = alignup(o + (size_t)N_EDGES * 4, 64);          // 6.4 MB
    size_t need1 = o;

    unsigned short* xh = (unsigned short*)(base + o_xh);
    int* es    = (int*)(base + o_es);
    int* off   = (int*)(base + o_off);
    int* C     = (int*)(base + o_C);
    int* btot  = (int*)(base + o_btot);
    unsigned short* Ah = (unsigned short*)(base + o_Ah);
    int* eb    = (int*)(base + o_eb);
    unsigned short* zh = xh;   // zh overlays dead xh

    if (ws_size >= need1) {
        // ---- fused cvt + count ----
        k_cvt_count<<<NPBLK + CVTBLK, 256, 0, stream>>>((const float4*)x, (uint4*)xh, dst, C);
        // ---- CSR build: multi-split, zero global atomics ----
        k_colscan<<<NBK2, NPBLK, 0, stream>>>(C, btot);
        k_scat<<<NPBLK, 256, 0, stream>>>(src, dst, C, btot, eb);
        k_fill3<<<NBK2, 256, 0, stream>>>(eb, btot, off, es);

        // ---- layer 1 aggregate: Ah = bf16(segsum(xh)) ----
        k_gather8<1><<<N_NODES / 32, 256, 0, stream>>>((const uint4*)xh, es, off, nullptr, nullptr, Ah);
        // ---- fused MLP: zh = bf16(relu(Ah*W1+b1)*W2)  (zh overlays dead xh) ----
        k_mlpB<<<N_NODES / MROWS, 256, 0, stream>>>(Ah, zh, W1, b1, W2);
        // ---- layer 2 aggregate + bias: out = b2 + segsum(zh) ----
        k_gather8<0><<<N_NODES / 32, 256, 0, stream>>>((const uint4*)zh, es, off, b2, out, nullptr);
    } else {
        // ---- fallback: atomic scatter (fp32, minimal workspace) ----
        float* A3 = (float*)d_ws;
        k_zero_f4<<<(nfeat4 + 255) / 256, 256, 0, stream>>>((float4*)A3, nfeat4);
        int threads = N_EDGES * 16;
        k_scatter64<<<(threads + 255) / 256, 256, 0, stream>>>(x, src, dst, A3);
        k_mlpF<<<N_NODES / MROWS, 256, 0, stream>>>(A3, W1, b1, W2);
        k_init_bias<<<(nfeat + 255) / 256, 256, 0, stream>>>(out, b2, nfeat);
        k_scatter64<<<(threads + 255) / 256, 256, 0, stream>>>(A3, src, dst, out);
    }
}

// Round 18
// 174.749 us; speedup vs baseline: 1.0730x; 1.0730x over previous
//
#include <hip/hip_runtime.h>

#define N_NODES 100000
#define N_EDGES 1600000
#define IN_F 64
#define HID 128
#define N_CLS 64

#define NPB2 256                                 // nodes per bucket (d >> 8)
#define NBK2 ((N_NODES + NPB2 - 1) / NPB2)       // 391
#define NPBLK 512                                // scatter blocks
#define PCHUNK (N_EDGES / NPBLK)                 // 3125 edges per block (exact)
#define CVTBLK ((N_NODES * 64 / 8 + 255) / 256)  // 3125 cvt blocks

// ================= bf16 helpers =================
__device__ __forceinline__ unsigned short f2bf(float f) {
    unsigned int u = __float_as_uint(f);
    u = (u + 0x7FFFu + ((u >> 16) & 1u)) >> 16;   // RNE
    return (unsigned short)u;
}
__device__ __forceinline__ float bf2f(unsigned short h) {
    return __uint_as_float(((unsigned int)h) << 16);
}

// ================= generic helpers =================
__global__ void k_zero_f4(float4* __restrict__ p, int n4) {
    int i = blockIdx.x * blockDim.x + threadIdx.x;
    if (i < n4) p[i] = make_float4(0.f, 0.f, 0.f, 0.f);
}
__global__ void k_init_bias(float* __restrict__ out, const float* __restrict__ b2, int n) {
    int i = blockIdx.x * blockDim.x + threadIdx.x;
    if (i < n) out[i] = b2[i & 63];
}

// ================= fused: fp32->bf16 convert + per-(block,bucket) counts =================
__global__ __launch_bounds__(256) void k_cvt_count(const float4* __restrict__ x4,
                                                   uint4* __restrict__ xh,
                                                   const int* __restrict__ dst,
                                                   int* __restrict__ C) {
    __shared__ int h[NBK2];
    const int t = threadIdx.x;
    if (blockIdx.x < NPBLK) {
        for (int i = t; i < NBK2; i += 256) h[i] = 0;
        __syncthreads();
        const int e0 = blockIdx.x * PCHUNK;
        int e1 = e0 + PCHUNK; if (e1 > N_EDGES) e1 = N_EDGES;
        for (int e = e0 + t; e < e1; e += 256) atomicAdd(&h[dst[e] >> 8], 1);
        __syncthreads();
        for (int i = t; i < NBK2; i += 256) C[blockIdx.x * NBK2 + i] = h[i];
    } else {
        int i = (blockIdx.x - NPBLK) * 256 + t;
        const int n8 = N_NODES * 64 / 8;
        if (i < n8) {
            float4 a = x4[2 * i], b = x4[2 * i + 1];
            uint4 o;
            o.x = (unsigned)f2bf(a.x) | ((unsigned)f2bf(a.y) << 16);
            o.y = (unsigned)f2bf(a.z) | ((unsigned)f2bf(a.w) << 16);
            o.z = (unsigned)f2bf(b.x) | ((unsigned)f2bf(b.y) << 16);
            o.w = (unsigned)f2bf(b.z) | ((unsigned)f2bf(b.w) << 16);
            xh[i] = o;
        }
    }
}

// 2) per-bucket column scan of C (in place -> exclusive offsets); emit totals
__global__ __launch_bounds__(NPBLK) void k_colscan(int* __restrict__ C,
                                                   int* __restrict__ btot) {
    __shared__ int sc[2][NPBLK];
    const int t = threadIdx.x;
    const int bucket = blockIdx.x;
    int v = C[t * NBK2 + bucket];
    sc[0][t] = v;
    __syncthreads();
    int cur = 0;
    for (int d = 1; d < NPBLK; d <<= 1) {
        int x = sc[cur][t];
        if (t >= d) x += sc[cur][t - d];
        sc[cur ^ 1][t] = x;
        __syncthreads();
        cur ^= 1;
    }
    C[t * NBK2 + bucket] = sc[cur][t] - v;            // exclusive within bucket
    if (t == NPBLK - 1) btot[bucket] = sc[cur][t];    // bucket total
}

// 3) scatter into exactly-reserved spans; boff recomputed in-block from btot
__global__ __launch_bounds__(256) void k_scat(const int* __restrict__ src,
                                              const int* __restrict__ dst,
                                              const int* __restrict__ C,
                                              const int* __restrict__ btot,
                                              int* __restrict__ eb) {
    __shared__ int gbase[NBK2];
    __shared__ int lcur[NBK2];
    __shared__ int sc[2][256];
    const int t = threadIdx.x;
    int v0 = (2 * t < NBK2) ? btot[2 * t] : 0;
    int v1 = (2 * t + 1 < NBK2) ? btot[2 * t + 1] : 0;
    int s = v0 + v1;
    sc[0][t] = s;
    __syncthreads();
    int cur = 0;
    for (int d = 1; d < 256; d <<= 1) {
        int x = sc[cur][t];
        if (t >= d) x += sc[cur][t - d];
        sc[cur ^ 1][t] = x;
        __syncthreads();
        cur ^= 1;
    }
    int exp = sc[cur][t] - s;
    if (2 * t < NBK2) {
        gbase[2 * t] = exp + C[blockIdx.x * NBK2 + 2 * t];
        lcur[2 * t] = 0;
    }
    if (2 * t + 1 < NBK2) {
        gbase[2 * t + 1] = exp + v0 + C[blockIdx.x * NBK2 + 2 * t + 1];
        lcur[2 * t + 1] = 0;
    }
    __syncthreads();
    const int e0 = blockIdx.x * PCHUNK;
    int e1 = e0 + PCHUNK; if (e1 > N_EDGES) e1 = N_EDGES;
    for (int e = e0 + t; e < e1; e += 256) {
        int d = dst[e];
        int b = d >> 8;
        int r = atomicAdd(&lcur[b], 1);
        eb[gbase[b] + r] = ((d & 255) << 17) | src[e];   // dstLow(8b) | src(17b)
    }
}

// 4) per-bucket: node hist + scan -> off; sort -> es; boff recomputed from btot
__global__ __launch_bounds__(256) void k_fill3(const int* __restrict__ eb,
                                               const int* __restrict__ btot,
                                               int* __restrict__ off,
                                               int* __restrict__ es) {
    __shared__ int ldeg[NPB2];
    __shared__ int sc[2][NPB2];
    __shared__ int sh_base, sh_end;
    const int t = threadIdx.x;
    const int b = blockIdx.x;

    int v0 = (2 * t < NBK2) ? btot[2 * t] : 0;
    int v1 = (2 * t + 1 < NBK2) ? btot[2 * t + 1] : 0;
    int s = v0 + v1;
    sc[0][t] = s;
    __syncthreads();
    int cur = 0;
    for (int d = 1; d < 256; d <<= 1) {
        int x = sc[cur][t];
        if (t >= d) x += sc[cur][t - d];
        sc[cur ^ 1][t] = x;
        __syncthreads();
        cur ^= 1;
    }
    int exp = sc[cur][t] - s;
    if (2 * t == b)     { sh_base = exp;          sh_end = exp + v0; }
    if (2 * t + 1 == b) { sh_base = exp + v0;     sh_end = exp + v0 + v1; }
    __syncthreads();
    const int bbase = sh_base, bend = sh_end;

    ldeg[t] = 0;
    __syncthreads();
    for (int i = bbase + t; i < bend; i += 256) atomicAdd(&ldeg[eb[i] >> 17], 1);
    __syncthreads();

    int v = ldeg[t];
    sc[0][t] = v;
    __syncthreads();
    cur = 0;
    for (int d = 1; d < NPB2; d <<= 1) {
        int x = sc[cur][t];
        if (t >= d) x += sc[cur][t - d];
        sc[cur ^ 1][t] = x;
        __syncthreads();
        cur ^= 1;
    }
    int ex = sc[cur][t] - v;

    const int n0 = b * NPB2;
    if (n0 + t < N_NODES) off[n0 + t] = bbase + ex;
    if (b == NBK2 - 1 && t == 0) off[N_NODES] = N_EDGES;

    ldeg[t] = ex;
    __syncthreads();

    for (int i = bbase + t; i < bend; i += 256) {
        int p = eb[i];
        int r = atomicAdd(&ldeg[p >> 17], 1);
        es[bbase + r] = p & 0x1FFFF;
    }
}

// ================= gather (bf16 feat, 8 nodes/wave, 8 lanes/node) =================
// OUTBF=1: write bf16 row to outh. OUTBF=0: write fp32 row (+bias) to out.
template <int OUTBF>
__global__ __launch_bounds__(256) void k_gather8(const uint4* __restrict__ feat,
                                                 const int* __restrict__ es,
                                                 const int* __restrict__ off,
                                                 const float* __restrict__ bias,
                                                 float* __restrict__ out,
                                                 unsigned short* __restrict__ outh) {
    const int wave = threadIdx.x >> 6;
    const int lane = threadIdx.x & 63;
    const int grp = lane >> 3;                 // 0..7
    const int l8 = lane & 7;
    const int n = blockIdx.x * 32 + wave * 8 + grp;   // 3125*32 == N_NODES exactly
    const int beg = off[n], end = off[n + 1];
    const int gb = grp << 3;
    float a0 = 0.f, a1 = 0.f, a2 = 0.f, a3 = 0.f;
    float a4 = 0.f, a5 = 0.f, a6 = 0.f, a7 = 0.f;
    for (int base = beg; base < end; base += 8) {
        int m = end - base; if (m > 8) m = 8;
        int id = (l8 < m) ? es[base + l8] : 0;
        int k = 0;
        for (; k + 4 <= m; k += 4) {
            int s0 = __shfl(id, gb | (k + 0));
            int s1 = __shfl(id, gb | (k + 1));
            int s2 = __shfl(id, gb | (k + 2));
            int s3 = __shfl(id, gb | (k + 3));
            uint4 u0 = feat[(unsigned)s0 * 8u + l8];
            uint4 u1 = feat[(unsigned)s1 * 8u + l8];
            uint4 u2 = feat[(unsigned)s2 * 8u + l8];
            uint4 u3 = feat[(unsigned)s3 * 8u + l8];
            a0 += (__uint_as_float(u0.x << 16) + __uint_as_float(u1.x << 16))
                + (__uint_as_float(u2.x << 16) + __uint_as_float(u3.x << 16));
            a1 += (__uint_as_float(u0.x & 0xFFFF0000u) + __uint_as_float(u1.x & 0xFFFF0000u))
                + (__uint_as_float(u2.x & 0xFFFF0000u) + __uint_as_float(u3.x & 0xFFFF0000u));
            a2 += (__uint_as_float(u0.y << 16) + __uint_as_float(u1.y << 16))
                + (__uint_as_float(u2.y << 16) + __uint_as_float(u3.y << 16));
            a3 += (__uint_as_float(u0.y & 0xFFFF0000u) + __uint_as_float(u1.y & 0xFFFF0000u))
                + (__uint_as_float(u2.y & 0xFFFF0000u) + __uint_as_float(u3.y & 0xFFFF0000u));
            a4 += (__uint_as_float(u0.z << 16) + __uint_as_float(u1.z << 16))
                + (__uint_as_float(u2.z << 16) + __uint_as_float(u3.z << 16));
            a5 += (__uint_as_float(u0.z & 0xFFFF0000u) + __uint_as_float(u1.z & 0xFFFF0000u))
                + (__uint_as_float(u2.z & 0xFFFF0000u) + __uint_as_float(u3.z & 0xFFFF0000u));
            a6 += (__uint_as_float(u0.w << 16) + __uint_as_float(u1.w << 16))
                + (__uint_as_float(u2.w << 16) + __uint_as_float(u3.w << 16));
            a7 += (__uint_as_float(u0.w & 0xFFFF0000u) + __uint_as_float(u1.w & 0xFFFF0000u))
                + (__uint_as_float(u2.w & 0xFFFF0000u) + __uint_as_float(u3.w & 0xFFFF0000u));
        }
        for (; k < m; ++k) {
            int s = __shfl(id, gb | k);
            uint4 u = feat[(unsigned)s * 8u + l8];
            a0 += __uint_as_float(u.x << 16);
            a1 += __uint_as_float(u.x & 0xFFFF0000u);
            a2 += __uint_as_float(u.y << 16);
            a3 += __uint_as_float(u.y & 0xFFFF0000u);
            a4 += __uint_as_float(u.z << 16);
            a5 += __uint_as_float(u.z & 0xFFFF0000u);
            a6 += __uint_as_float(u.w << 16);
            a7 += __uint_as_float(u.w & 0xFFFF0000u);
        }
    }
    if (OUTBF) {
        uint4 w;
        w.x = (unsigned)f2bf(a0) | ((unsigned)f2bf(a1) << 16);
        w.y = (unsigned)f2bf(a2) | ((unsigned)f2bf(a3) << 16);
        w.z = (unsigned)f2bf(a4) | ((unsigned)f2bf(a5) << 16);
        w.w = (unsigned)f2bf(a6) | ((unsigned)f2bf(a7) << 16);
        *(uint4*)&outh[(size_t)n * 64 + l8 * 8] = w;
    } else {
        if (bias) {
            float4 b0 = *(const float4*)&bias[l8 * 8];
            float4 b1 = *(const float4*)&bias[l8 * 8 + 4];
            a0 += b0.x; a1 += b0.y; a2 += b0.z; a3 += b0.w;
            a4 += b1.x; a5 += b1.y; a6 += b1.z; a7 += b1.w;
        }
        float4 o0, o1;
        o0.x = a0; o0.y = a1; o0.z = a2; o0.w = a3;
        o1.x = a4; o1.y = a5; o1.z = a6; o1.w = a7;
        *(float4*)&out[(size_t)n * 64 + l8 * 8] = o0;
        *(float4*)&out[(size_t)n * 64 + l8 * 8 + 4] = o1;
    }
}

// ================= fallback atomic scatter =================
__global__ void k_scatter64(const float* __restrict__ feat,
                            const int* __restrict__ src,
                            const int* __restrict__ dst,
                            float* __restrict__ out) {
    int i = blockIdx.x * blockDim.x + threadIdx.x;
    int e = i >> 4;
    if (e >= N_EDGES) return;
    int j = (i & 15) << 2;
    int s = src[e];
    int d = dst[e];
    float4 v = *reinterpret_cast<const float4*>(feat + (size_t)s * 64 + j);
    float* o = out + (size_t)d * 64 + j;
    atomicAdd(o + 0, v.x);
    atomicAdd(o + 1, v.y);
    atomicAdd(o + 2, v.z);
    atomicAdd(o + 3, v.w);
}

// ================= split GEMMs =================
#define MROWS 32
#define XS_S 68      // float stride (fallback MLP)
#define XSB_S 72     // ushort stride for bf16 x rows (144 B, 16B-aligned)
#define HS2_S 152    // ushort stride for h rows in gemm2

__device__ __forceinline__ void fma4(float4& a, float s, const float4& wv) {
    a.x = fmaf(s, wv.x, a.x);
    a.y = fmaf(s, wv.y, a.y);
    a.z = fmaf(s, wv.z, a.z);
    a.w = fmaf(s, wv.w, a.w);
}

// GEMM1: H(bf16, stride 128) = relu(Ah(bf16)*W1 + b1)
__global__ __launch_bounds__(256, 4) void k_gemm1(const unsigned short* __restrict__ Ah,
                                                  unsigned short* __restrict__ H,
                                                  const float* __restrict__ W1,
                                                  const float* __restrict__ b1) {
    __shared__ float Ws[64 * 128];                  // 32 KB
    __shared__ unsigned short xs[MROWS * XSB_S];    // 4.6 KB bf16 x
    __shared__ float b1s[128];
    const int t = threadIdx.x;
    const int row0 = blockIdx.x * MROWS;

    {
        const float4* w4 = (const float4*)W1;
        float4* s4 = (float4*)Ws;
        for (int i = t; i < 2048; i += 256) s4[i] = w4[i];
    }
    if (t < 128) b1s[t] = b1[t];
    // stage Ah rows: 32 rows x 64 bf16 = 256 uint4 (one per thread)
    {
        int r = t >> 3, k8 = t & 7;
        uint4 v = *(const uint4*)&Ah[(size_t)(row0 + r) * 64 + k8 * 8];
        *(uint4*)&xs[r * XSB_S + k8 * 8] = v;
    }
    __syncthreads();

    const int rg = t >> 5, cg = t & 31;
    const int r0 = rg * 4, c0 = cg * 4;
    float4 bv = *(const float4*)&b1s[c0];
    float4 acc0 = bv, acc1 = bv, acc2 = bv, acc3 = bv;
#pragma unroll 4
    for (int k4 = 0; k4 < 16; ++k4) {
        ushort4 ua0 = *(const ushort4*)&xs[(r0 + 0) * XSB_S + k4 * 4];
        ushort4 ua1 = *(const ushort4*)&xs[(r0 + 1) * XSB_S + k4 * 4];
        ushort4 ua2 = *(const ushort4*)&xs[(r0 + 2) * XSB_S + k4 * 4];
        ushort4 ua3 = *(const ushort4*)&xs[(r0 + 3) * XSB_S + k4 * 4];
        float4 w0 = *(const float4*)&Ws[(k4 * 4 + 0) * 128 + c0];
        float4 w1 = *(const float4*)&Ws[(k4 * 4 + 1) * 128 + c0];
        float4 w2 = *(const float4*)&Ws[(k4 * 4 + 2) * 128 + c0];
        float4 w3 = *(const float4*)&Ws[(k4 * 4 + 3) * 128 + c0];
        fma4(acc0, bf2f(ua0.x), w0); fma4(acc0, bf2f(ua0.y), w1);
        fma4(acc0, bf2f(ua0.z), w2); fma4(acc0, bf2f(ua0.w), w3);
        fma4(acc1, bf2f(ua1.x), w0); fma4(acc1, bf2f(ua1.y), w1);
        fma4(acc1, bf2f(ua1.z), w2); fma4(acc1, bf2f(ua1.w), w3);
        fma4(acc2, bf2f(ua2.x), w0); fma4(acc2, bf2f(ua2.y), w1);
        fma4(acc2, bf2f(ua2.z), w2); fma4(acc2, bf2f(ua2.w), w3);
        fma4(acc3, bf2f(ua3.x), w0); fma4(acc3, bf2f(ua3.y), w1);
        fma4(acc3, bf2f(ua3.z), w2); fma4(acc3, bf2f(ua3.w), w3);
    }
    ushort4 o;
    o.x = f2bf(fmaxf(acc0.x, 0.f)); o.y = f2bf(fmaxf(acc0.y, 0.f));
    o.z = f2bf(fmaxf(acc0.z, 0.f)); o.w = f2bf(fmaxf(acc0.w, 0.f));
    *(ushort4*)&H[(size_t)(row0 + r0 + 0) * 128 + c0] = o;
    o.x = f2bf(fmaxf(acc1.x, 0.f)); o.y = f2bf(fmaxf(acc1.y, 0.f));
    o.z = f2bf(fmaxf(acc1.z, 0.f)); o.w = f2bf(fmaxf(acc1.w, 0.f));
    *(ushort4*)&H[(size_t)(row0 + r0 + 1) * 128 + c0] = o;
    o.x = f2bf(fmaxf(acc2.x, 0.f)); o.y = f2bf(fmaxf(acc2.y, 0.f));
    o.z = f2bf(fmaxf(acc2.z, 0.f)); o.w = f2bf(fmaxf(acc2.w, 0.f));
    *(ushort4*)&H[(size_t)(row0 + r0 + 2) * 128 + c0] = o;
    o.x = f2bf(fmaxf(acc3.x, 0.f)); o.y = f2bf(fmaxf(acc3.y, 0.f));
    o.z = f2bf(fmaxf(acc3.z, 0.f)); o.w = f2bf(fmaxf(acc3.w, 0.f));
    *(ushort4*)&H[(size_t)(row0 + r0 + 3) * 128 + c0] = o;
}

// GEMM2: zh(bf16) = H(bf16) * W2
__global__ __launch_bounds__(256, 3) void k_gemm2(const unsigned short* __restrict__ H,
                                                  unsigned short* __restrict__ zh,
                                                  const float* __restrict__ W2) {
    __shared__ float Ws[128 * 64];
    __shared__ unsigned short hsb[MROWS * HS2_S];
    const int t = threadIdx.x;
    const int row0 = blockIdx.x * MROWS;

    {
        const float4* w4 = (const float4*)W2;
        float4* s4 = (float4*)Ws;
        for (int i = t; i < 2048; i += 256) s4[i] = w4[i];
    }
#pragma unroll
    for (int c = 0; c < 2; ++c) {
        int lin = t + c * 256;
        int r = lin >> 4, k8 = lin & 15;
        uint4 v = *(const uint4*)(H + (size_t)(row0 + r) * 128 + k8 * 8);
        *(uint4*)&hsb[r * HS2_S + k8 * 8] = v;
    }
    __syncthreads();

    const int rg = t >> 4, cg = t & 15;
    const int r0 = rg * 2, c0 = cg * 4;
    float4 acc0 = make_float4(0.f, 0.f, 0.f, 0.f);
    float4 acc1 = make_float4(0.f, 0.f, 0.f, 0.f);
#pragma unroll 4
    for (int k4 = 0; k4 < 32; ++k4) {
        ushort4 u0 = *(const ushort4*)&hsb[(r0 + 0) * HS2_S + k4 * 4];
        ushort4 u1 = *(const ushort4*)&hsb[(r0 + 1) * HS2_S + k4 * 4];
        float4 w0 = *(const float4*)&Ws[(k4 * 4 + 0) * 64 + c0];
        float4 w1 = *(const float4*)&Ws[(k4 * 4 + 1) * 64 + c0];
        float4 w2 = *(const float4*)&Ws[(k4 * 4 + 2) * 64 + c0];
        float4 w3 = *(const float4*)&Ws[(k4 * 4 + 3) * 64 + c0];
        fma4(acc0, bf2f(u0.x), w0); fma4(acc0, bf2f(u0.y), w1);
        fma4(acc0, bf2f(u0.z), w2); fma4(acc0, bf2f(u0.w), w3);
        fma4(acc1, bf2f(u1.x), w0); fma4(acc1, bf2f(u1.y), w1);
        fma4(acc1, bf2f(u1.z), w2); fma4(acc1, bf2f(u1.w), w3);
    }
    ushort4 o0, o1;
    o0.x = f2bf(acc0.x); o0.y = f2bf(acc0.y); o0.z = f2bf(acc0.z); o0.w = f2bf(acc0.w);
    o1.x = f2bf(acc1.x); o1.y = f2bf(acc1.y); o1.z = f2bf(acc1.z); o1.w = f2bf(acc1.w);
    *(ushort4*)&zh[(size_t)(row0 + r0 + 0) * 64 + c0] = o0;
    *(ushort4*)&zh[(size_t)(row0 + r0 + 1) * 64 + c0] = o1;
}

// fp32 in-place MLP (fallback)
__global__ __launch_bounds__(256, 2) void k_mlpF(float* __restrict__ A,
                                                 const float* __restrict__ W1,
                                                 const float* __restrict__ b1,
                                                 const float* __restrict__ W2) {
    __shared__ float Ws[64 * 128];
    __shared__ float xs[MROWS * XS_S];
    __shared__ float hs[MROWS * 132];
    __shared__ float b1s[128];
    const int t = threadIdx.x;
    const int row0 = blockIdx.x * MROWS;

    {
        const float4* w4 = (const float4*)W1;
        float4* s4 = (float4*)Ws;
        for (int i = t; i < 2048; i += 256) s4[i] = w4[i];
    }
    if (t < 128) b1s[t] = b1[t];
#pragma unroll
    for (int c = 0; c < 2; ++c) {
        int lin = t + c * 256;
        int r = lin >> 4, k4 = lin & 15;
        float4 v = *(const float4*)(A + (size_t)(row0 + r) * 64 + k4 * 4);
        *(float4*)&xs[r * XS_S + k4 * 4] = v;
    }
    __syncthreads();
    {
        const int rg = t >> 5, cg = t & 31;
        const int r0 = rg * 4, c0 = cg * 4;
        float4 bv = *(const float4*)&b1s[c0];
        float4 acc0 = bv, acc1 = bv, acc2 = bv, acc3 = bv;
#pragma unroll 4
        for (int k4 = 0; k4 < 16; ++k4) {
            float4 a0 = *(const float4*)&xs[(r0 + 0) * XS_S + k4 * 4];
            float4 a1 = *(const float4*)&xs[(r0 + 1) * XS_S + k4 * 4];
            float4 a2 = *(const float4*)&xs[(r0 + 2) * XS_S + k4 * 4];
            float4 a3 = *(const float4*)&xs[(r0 + 3) * XS_S + k4 * 4];
            float4 w0 = *(const float4*)&Ws[(k4 * 4 + 0) * 128 + c0];
            float4 w1 = *(const float4*)&Ws[(k4 * 4 + 1) * 128 + c0];
            float4 w2 = *(const float4*)&Ws[(k4 * 4 + 2) * 128 + c0];
            float4 w3 = *(const float4*)&Ws[(k4 * 4 + 3) * 128 + c0];
            fma4(acc0, a0.x, w0); fma4(acc0, a0.y, w1); fma4(acc0, a0.z, w2); fma4(acc0, a0.w, w3);
            fma4(acc1, a1.x, w0); fma4(acc1, a1.y, w1); fma4(acc1, a1.z, w2); fma4(acc1, a1.w, w3);
            fma4(acc2, a2.x, w0); fma4(acc2, a2.y, w1); fma4(acc2, a2.z, w2); fma4(acc2, a2.w, w3);
            fma4(acc3, a3.x, w0); fma4(acc3, a3.y, w1); fma4(acc3, a3.z, w2); fma4(acc3, a3.w, w3);
        }
        float4 h;
        h.x = fmaxf(acc0.x, 0.f); h.y = fmaxf(acc0.y, 0.f); h.z = fmaxf(acc0.z, 0.f); h.w = fmaxf(acc0.w, 0.f);
        *(float4*)&hs[(r0 + 0) * 132 + c0] = h;
        h.x = fmaxf(acc1.x, 0.f); h.y = fmaxf(acc1.y, 0.f); h.z = fmaxf(acc1.z, 0.f); h.w = fmaxf(acc1.w, 0.f);
        *(float4*)&hs[(r0 + 1) * 132 + c0] = h;
        h.x = fmaxf(acc2.x, 0.f); h.y = fmaxf(acc2.y, 0.f); h.z = fmaxf(acc2.z, 0.f); h.w = fmaxf(acc2.w, 0.f);
        *(float4*)&hs[(r0 + 2) * 132 + c0] = h;
        h.x = fmaxf(acc3.x, 0.f); h.y = fmaxf(acc3.y, 0.f); h.z = fmaxf(acc3.z, 0.f); h.w = fmaxf(acc3.w, 0.f);
        *(float4*)&hs[(r0 + 3) * 132 + c0] = h;
    }
    __syncthreads();
    {
        const float4* w4 = (const float4*)W2;
        float4* s4 = (float4*)Ws;
        for (int i = t; i < 2048; i += 256) s4[i] = w4[i];
    }
    __syncthreads();
    {
        const int rg = t >> 4, cg = t & 15;
        const int r0 = rg * 2, c0 = cg * 4;
        float4 acc0 = make_float4(0.f, 0.f, 0.f, 0.f);
        float4 acc1 = make_float4(0.f, 0.f, 0.f, 0.f);
#pragma unroll 4
        for (int k4 = 0; k4 < 32; ++k4) {
            float4 h0 = *(const float4*)&hs[(r0 + 0) * 132 + k4 * 4];
            float4 h1 = *(const float4*)&hs[(r0 + 1) * 132 + k4 * 4];
            float4 w0 = *(const float4*)&Ws[(k4 * 4 + 0) * 64 + c0];
            float4 w1 = *(const float4*)&Ws[(k4 * 4 + 1) * 64 + c0];
            float4 w2 = *(const float4*)&Ws[(k4 * 4 + 2) * 64 + c0];
            float4 w3 = *(const float4*)&Ws[(k4 * 4 + 3) * 64 + c0];
            fma4(acc0, h0.x, w0); fma4(acc0, h0.y, w1); fma4(acc0, h0.z, w2); fma4(acc0, h0.w, w3);
            fma4(acc1, h1.x, w0); fma4(acc1, h1.y, w1); fma4(acc1, h1.z, w2); fma4(acc1, h1.w, w3);
        }
        *(float4*)(A + (size_t)(row0 + r0 + 0) * 64 + c0) = acc0;
        *(float4*)(A + (size_t)(row0 + r0 + 1) * 64 + c0) = acc1;
    }
}

static inline size_t alignup(size_t v, size_t a) { return (v + a - 1) & ~(a - 1); }

extern "C" void kernel_launch(void* const* d_in, const int* in_sizes, int n_in,
                              void* d_out, int out_size, void* d_ws, size_t ws_size,
                              hipStream_t stream) {
    const float* x  = (const float*)d_in[0];
    const float* W1 = (const float*)d_in[1];
    const float* b1 = (const float*)d_in[2];
    const float* W2 = (const float*)d_in[3];
    const float* b2 = (const float*)d_in[4];
    const int* src  = (const int*)d_in[5];
    const int* dst  = (const int*)d_in[6];
    float* out = (float*)d_out;

    const int nfeat = N_NODES * 64;
    const int nfeat4 = nfeat / 4;

    // ---- tier-1 layout (64B-aligned fields) ----
    char* base = (char*)d_ws;
    size_t o = 0;
    size_t o_xh   = o;   o = alignup(o + (size_t)nfeat * 2, 64);            // 12.8 MB (zh aliases)
    size_t o_es   = o;   o = alignup(o + (size_t)N_EDGES * 4, 64);          // 6.4 MB
    size_t o_off  = o;   o = alignup(o + (size_t)(N_NODES + 1) * 4, 64);
    size_t o_C    = o;   o = alignup(o + (size_t)NPBLK * NBK2 * 4, 64);     // 800 KB
    size_t o_btot = o;   o = alignup(o + (size_t)NBK2 * 4, 64);
    size_t o_Ah   = o;   o = alignup(o + (size_t)nfeat * 2, 64);            // 12.8 MB bf16 agg
    size_t o_shrd = o;   o = alignup(o + (size_t)N_NODES * 128 * 2, 64);    // eb (6.4) / H (25.6) share
    size_t need1 = o;

    unsigned short* xh = (unsigned short*)(base + o_xh);
    int* es    = (int*)(base + o_es);
    int* off   = (int*)(base + o_off);
    int* C     = (int*)(base + o_C);
    int* btot  = (int*)(base + o_btot);
    unsigned short* Ah = (unsigned short*)(base + o_Ah);
    int* eb    = (int*)(base + o_shrd);
    unsigned short* H = (unsigned short*)(base + o_shrd);   // overlays dead eb
    unsigned short* zh = xh;                                 // overlays dead xh

    if (ws_size >= need1) {
        // ---- fused cvt + count ----
        k_cvt_count<<<NPBLK + CVTBLK, 256, 0, stream>>>((const float4*)x, (uint4*)xh, dst, C);
        // ---- CSR build: multi-split, zero global atomics ----
        k_colscan<<<NBK2, NPBLK, 0, stream>>>(C, btot);
        k_scat<<<NPBLK, 256, 0, stream>>>(src, dst, C, btot, eb);
        k_fill3<<<NBK2, 256, 0, stream>>>(eb, btot, off, es);

        // ---- layer 1 aggregate: Ah = bf16(segsum(xh)) ----
        k_gather8<1><<<N_NODES / 32, 256, 0, stream>>>((const uint4*)xh, es, off, nullptr, nullptr, Ah);
        // ---- GEMM1: H = bf16(relu(Ah*W1+b1))  (H overlays dead eb) ----
        k_gemm1<<<N_NODES / MROWS, 256, 0, stream>>>(Ah, H, W1, b1);
        // ---- GEMM2: zh = bf16(H*W2)  (zh overlays dead xh) ----
        k_gemm2<<<N_NODES / MROWS, 256, 0, stream>>>(H, zh, W2);
        // ---- layer 2 aggregate + bias: out = b2 + segsum(zh) ----
        k_gather8<0><<<N_NODES / 32, 256, 0, stream>>>((const uint4*)zh, es, off, b2, out, nullptr);
    } else {
        // ---- fallback: atomic scatter (fp32, minimal workspace) ----
        float* A3 = (float*)d_ws;
        k_zero_f4<<<(nfeat4 + 255) / 256, 256, 0, stream>>>((float4*)A3, nfeat4);
        int threads = N_EDGES * 16;
        k_scatter64<<<(threads + 255) / 256, 256, 0, stream>>>(x, src, dst, A3);
        k_mlpF<<<N_NODES / MROWS, 256, 0, stream>>>(A3, W1, b1, W2);
        k_init_bias<<<(nfeat + 255) / 256, 256, 0, stream>>>(out, b2, nfeat);
        k_scatter64<<<(threads + 255) / 256, 256, 0, stream>>>(A3, src, dst, out);
    }
}